// Round 7
// baseline (632.049 us; speedup 1.0000x reference)
//
#include <hip/hip_runtime.h>

// Shapes fixed by the reference setup.
#define BB 32
#define HH 16
#define NN 1024
#define DD 128

// One block per (b,h) row: 1024 threads = 16 waves = 32 half-waves.
// KEY CHANGE (R7): t is read from HBM exactly ONCE and held in registers
// (32 float4 = 128 VGPRs/thread) across the softmax; the scale phase writes
// back the held values. This halves read-path traffic (prior versions
// re-read t from L3 in the scale phase; model: read fabric ~3.1 TB/s
// regardless of HBM-vs-L3 source, writes ~6.4 TB/s and overlap).
//   Phase A: padd[b] = first index with padding==0 (else N), block-min reduce.
//   Phase B: load 32 rows/thread-group into regs; score via pair-merged butterfly.
//   Phase C: masked softmax in LDS -> factor[n] = 1 + attn[n].
//   Phase D: out = v * factor from REGISTERS (no re-read).
__global__ __launch_bounds__(1024) void fused_kernel(const float* __restrict__ t,
                                                     const int* __restrict__ padding,
                                                     const float* __restrict__ w2,
                                                     float* __restrict__ out) {
    const int bh   = blockIdx.x;        // 0..B*H-1
    const int b    = bh >> 4;           // H = 16
    const int tid  = threadIdx.x;       // 0..1023
    const int wid  = tid >> 6;          // wave 0..15
    const int lane = tid & 63;

    __shared__ float s_fac[NN];         // scores, then factors
    __shared__ int   red_i[16];
    __shared__ float red_f[16];

    const float* trow = t + (long)bh * NN * DD;

    // ---- Phase A: per-wave part of padd reduction ----
    int lm = (padding[b * NN + tid] == 0) ? tid : NN;
#pragma unroll
    for (int off = 32; off; off >>= 1) lm = min(lm, __shfl_xor(lm, off));
    if (lane == 0) red_i[wid] = lm;

    // ---- Phase B: half-wave (32 lanes) owns 32 consecutive rows. ----
    // Thread (hw, l) holds row hw*32+k, float4-column l, for k = 0..31.
    const int hw = tid >> 5;            // 0..31
    const int l  = tid & 31;
    const float4 wv = ((const float4*)w2)[l];
    const float4* rowp = (const float4*)(trow + (long)(hw * 32) * DD);

    float4 v[32];                       // 128 VGPRs payload, static indices only
#pragma unroll
    for (int k = 0; k < 32; ++k) v[k] = rowp[k * 32 + l];

    // Pair-merged butterfly: 5 shuffles reduce TWO rows at once.
    // Dots computed inside the loop so loads are consumed progressively
    // (compiler emits decreasing vmcnt waits) and p live-range stays short.
#pragma unroll
    for (int pr = 0; pr < 16; ++pr) {
        const float a  = v[2 * pr].x     * wv.x + v[2 * pr].y     * wv.y
                       + v[2 * pr].z     * wv.z + v[2 * pr].w     * wv.w;
        const float bq = v[2 * pr + 1].x * wv.x + v[2 * pr + 1].y * wv.y
                       + v[2 * pr + 1].z * wv.z + v[2 * pr + 1].w * wv.w;
        float x = (l < 16) ? a : bq;
        float y = (l < 16) ? bq : a;
        x += __shfl_xor(y, 16);
        x += __shfl_xor(x, 8);
        x += __shfl_xor(x, 4);
        x += __shfl_xor(x, 2);
        x += __shfl_xor(x, 1);
        const int n = hw * 32 + 2 * pr;
        if (l == 0)  s_fac[n]     = x;
        if (l == 16) s_fac[n + 1] = x;
    }
    __syncthreads();                    // covers red_i and s_fac writes

    int padd = NN;
#pragma unroll
    for (int k = 0; k < 16; ++k) padd = min(padd, red_i[k]);

    // ---- Phase C: masked softmax over s_fac, one score per thread ----
    const float sc  = s_fac[tid];
    const float NEG = -3.4e38f;
    float m = (tid < padd) ? sc : NEG;
#pragma unroll
    for (int off = 32; off; off >>= 1) m = fmaxf(m, __shfl_xor(m, off));
    if (lane == 0) red_f[wid] = m;
    __syncthreads();
    float M = NEG;
#pragma unroll
    for (int k = 0; k < 16; ++k) M = fmaxf(M, red_f[k]);
    __syncthreads();                    // before red_f reuse

    const float e = (tid < padd) ? __expf(sc - M) : 0.f;
    float s = e;
#pragma unroll
    for (int off = 32; off; off >>= 1) s += __shfl_xor(s, off);
    if (lane == 0) red_f[wid] = s;
    __syncthreads();
    float S = 0.f;
#pragma unroll
    for (int k = 0; k < 16; ++k) S += red_f[k];

    const float inv = (S > 0.f) ? (1.0f / S) : 0.f;   // padd==0 never occurs here
    s_fac[tid] = 1.f + e * inv;         // masked n -> exactly 1
    __syncthreads();

    // ---- Phase D: out = v * factor, straight from registers ----
    float4* o4row = (float4*)(out + (long)bh * NN * DD + (long)(hw * 32) * DD);
#pragma unroll
    for (int k = 0; k < 32; ++k) {
        const float f = s_fac[hw * 32 + k];   // broadcast within 32-lane group
        float4 w = v[k];
        w.x *= f; w.y *= f; w.z *= f; w.w *= f;
        o4row[k * 32 + l] = w;
    }
}

extern "C" void kernel_launch(void* const* d_in, const int* in_sizes, int n_in,
                              void* d_out, int out_size, void* d_ws, size_t ws_size,
                              hipStream_t stream) {
    // inputs: 0 t_1 (unused — softmax shift-invariance), 1 t, 2 padding, 3 N,
    //         4 concat_w (w1 unused | w2), 5 concat_b (unused — cancels)
    const float* t       = (const float*)d_in[1];
    const int*   padding = (const int*)d_in[2];
    const float* cw      = (const float*)d_in[4];
    float*       out     = (float*)d_out;

    fused_kernel<<<BB * HH, 1024, 0, stream>>>(t, padding, cw + DD, out);
}